// Round 3
// baseline (515.296 us; speedup 1.0000x reference)
//
#include <hip/hip_runtime.h>
#include <hip/hip_bf16.h>
#include <string.h>

// Problem constants (fixed by setup_inputs: B=16, T=16, W=256)
#define WDIM 256
#define FRAME (WDIM * WDIM)        // 65536 elems per frame
#define NFRAMES 256                // B*T
#define NTOT ((long long)NFRAMES * FRAME)  // 16777216
#define NBLK 2048                  // 8 sub-blocks per frame
#define SUBV4 2048                 // float4 per sub-block (32 KiB)

// ws layout:
//   [0,1024)        int arrive[256]   -- per-frame record counter (memset 0)
//   [1024,1028)     int done          -- global completion ticket (memset 0)
//   [4096,36864)    float4 blk[2048]  -- per-block stats records (all rewritten)
//   [36864,53248)   double bsum[2048] -- per-block partials (all rewritten)

__device__ inline unsigned int pack_bf16x2(float a, float b) {
    __hip_bfloat162 h = __float22bfloat162_rn(make_float2(a, b));
    unsigned int u; memcpy(&u, &h, 4); return u;
}

// One kernel does everything. 2048 blocks x 256 threads, __launch_bounds__(256,8)
// => 8 blocks/CU * 256 CU = 2048: the whole grid is co-resident (tiny LDS,
// VGPR capped at 64), so per-frame producer/consumer sync via device-scope
// atomics cannot deadlock. Target is read from HBM exactly once and kept in a
// bf16 register stash across the sync point (round-0-verified numerics).
__global__ __launch_bounds__(256, 8)
void floss_all(const float* __restrict__ input, const float* __restrict__ target,
               int* arrive, int* done,
               float4* __restrict__ blk, double* __restrict__ bsum,
               float* __restrict__ out) {
    const int bid = blockIdx.x;
    const int fid = bid >> 3, sub = bid & 7;
    const int tid = threadIdx.x;
    const int lane = tid & 63, wave = tid >> 6;

    const float4* __restrict__ t4 =
        (const float4*)(target + (size_t)fid * FRAME) + sub * SUBV4;
    const float4* __restrict__ p4 =
        (const float4*)(input + (size_t)fid * FRAME) + sub * SUBV4;

    __shared__ float s_wm[4];
    __shared__ float s_cnt, s_sr, s_sc;
    __shared__ float s_xy[2];
    __shared__ float s_acc[4];
    __shared__ double s_d[4];
    __shared__ int s_last;

    if (tid == 0) { s_cnt = 0.f; s_sr = 0.f; s_sc = 0.f; }

    // ---- Pass 1: stream target once; bf16 stash in regs; fmax scan ----
    // elem f = sub*8192 + k*1024 + 4*tid + j -> row = sub*32+4k+wave,
    // col = (tid&63)*4 + j
    unsigned int st16[16];            // 32 target values as bf16 pairs
    float lmax = -1.f;
    #pragma unroll
    for (int k = 0; k < 8; ++k) {
        const float4 v = t4[k * 256 + tid];
        lmax = fmaxf(lmax, fmaxf(fmaxf(v.x, v.y), fmaxf(v.z, v.w)));
        st16[2 * k]     = pack_bf16x2(v.x, v.y);
        st16[2 * k + 1] = pack_bf16x2(v.z, v.w);
    }
    float wm = lmax;
    #pragma unroll
    for (int off = 32; off > 0; off >>= 1) wm = fmaxf(wm, __shfl_down(wm, off));
    if (lane == 0) s_wm[wave] = wm;
    __syncthreads();   // covers s_wm + s_cnt init
    const float bmax = fmaxf(fmaxf(s_wm[0], s_wm[1]), fmaxf(s_wm[2], s_wm[3]));

    // prefetch input chunks 0/1 (independent of stats; hides HBM latency
    // under the rescan + spin)
    float4 pA = p4[tid], pB = p4[256 + tid];

    // ---- Rescan (rare): exact fp32 tie stats vs block max ----
    if (lmax == bmax) {   // ~1 thread per block; most waves skip via execz
        float cnt = 0.f, sr = 0.f, sc = 0.f;
        const float rowb = (float)(sub * 32 + wave);
        const float colb = (float)((tid & 63) * 4);
        for (int k = 0; k < 8; ++k) {          // re-read own 128 B (L2-hot)
            const float4 v = t4[k * 256 + tid];
            const float row = rowb + (float)(4 * k);
            const float vv[4] = {v.x, v.y, v.z, v.w};
            #pragma unroll
            for (int j = 0; j < 4; ++j)
                if (vv[j] == bmax) { cnt += 1.f; sr += row; sc += colb + (float)j; }
        }
        atomicAdd(&s_cnt, cnt); atomicAdd(&s_sr, sr); atomicAdd(&s_sc, sc);
    }
    __syncthreads();

    // ---- Publish record; spin for the frame's 8 records; combine ----
    if (tid == 0) {
        blk[bid] = make_float4(bmax, s_cnt, s_sr, s_sc);
        __threadfence();  // release: record visible device-wide before count
        __hip_atomic_fetch_add(&arrive[fid], 1, __ATOMIC_RELEASE,
                               __HIP_MEMORY_SCOPE_AGENT);
        int spins = 0;
        while (__hip_atomic_load(&arrive[fid], __ATOMIC_ACQUIRE,
                                 __HIP_MEMORY_SCOPE_AGENT) < 8) {
            __builtin_amdgcn_s_sleep(2);
            if (++spins > (1 << 22)) break;   // fail loud (absmax), never hang
        }
        // combine: max of 8 block maxes; sum stats of matching blocks.
        // Exact float compares + exact small-int sums == round-2 bitwise.
        float4 r[8];
        float fm = -1.f;
        #pragma unroll
        for (int i = 0; i < 8; ++i) { r[i] = blk[(fid << 3) + i]; fm = fmaxf(fm, r[i].x); }
        float cnt = 0.f, sr = 0.f, sc = 0.f;
        #pragma unroll
        for (int i = 0; i < 8; ++i)
            if (r[i].x == fm) { cnt += r[i].y; sr += r[i].z; sc += r[i].w; }
        const float rc = __builtin_amdgcn_rcpf(cnt);   // cnt: small exact int
        s_xy[0] = sr * rc;   // mean row
        s_xy[1] = sc * rc;   // mean col
    }
    __syncthreads();

    // ---- Pass 2: BCE; input double-buffered from HBM, target from regs ----
    const float x = s_xy[0], y = s_xy[1];
    const float rowb = (float)(sub * 32 + wave);
    float dc2[4];
    #pragma unroll
    for (int j = 0; j < 4; ++j) {
        const float d = (float)((tid & 63) * 4 + j) - y;
        dc2[j] = d * d;
    }

    float acc0 = 0.f, acc1 = 0.f;
    #pragma unroll
    for (int k = 0; k < 8; ++k) {
        const float4 pv = (k & 1) ? pB : pA;
        if (k < 6) {    // keep 2 chunks in flight
            if (k & 1) pB = p4[(k + 2) * 256 + tid];
            else       pA = p4[(k + 2) * 256 + tid];
        }
        const unsigned int w0 = st16[2 * k], w1 = st16[2 * k + 1];
        const float tt[4] = {
            __uint_as_float(w0 << 16), __uint_as_float(w0 & 0xffff0000u),
            __uint_as_float(w1 << 16), __uint_as_float(w1 & 0xffff0000u)
        };
        const float pp[4] = {pv.x, pv.y, pv.z, pv.w};
        const float dr = rowb + (float)(4 * k) - x;
        const float dr2 = dr * dr;
        #pragma unroll
        for (int j = 0; j < 4; ++j) {
            const float dist = __builtin_amdgcn_sqrtf(dr2 + dc2[j]);
            const float w = 256.0f * __builtin_amdgcn_rcpf(dist + 1.0f);
            const float p = pp[j];
            const float lp  = fmaxf(__logf(p), -100.0f);          // v_log_f32
            const float l1p = fmaxf(__logf(1.0f - p), -100.0f);   // exact 1-p for p>=0.5
            // t*lp + (1-t)*l1p == l1p + t*(lp - l1p)
            if (j & 1) acc1 += w * fmaf(tt[j], lp - l1p, l1p);
            else       acc0 += w * fmaf(tt[j], lp - l1p, l1p);
        }
    }

    float local = acc0 + acc1;
    #pragma unroll
    for (int off = 32; off > 0; off >>= 1) local += __shfl_down(local, off);
    if (lane == 0) s_acc[wave] = local;
    __syncthreads();

    // ---- Last-arriving block reduces the 2048 partials (folds old K3) ----
    if (tid == 0) {
        bsum[bid] = (double)(s_acc[0] + s_acc[1] + s_acc[2] + s_acc[3]);
        __threadfence();  // release partial before ticket
        const int t = __hip_atomic_fetch_add(done, 1, __ATOMIC_ACQ_REL,
                                             __HIP_MEMORY_SCOPE_AGENT);
        s_last = (t == NBLK - 1) ? 1 : 0;
    }
    __syncthreads();
    if (s_last) {                       // block-uniform branch
        __threadfence();                // acquire: see all 2048 partials
        double v = 0.0;
        #pragma unroll
        for (int i = 0; i < 8; ++i) v += bsum[tid + 256 * i];
        #pragma unroll
        for (int off = 32; off > 0; off >>= 1) v += __shfl_down(v, off);
        if (lane == 0) s_d[wave] = v;
        __syncthreads();
        if (tid == 0)
            out[0] = (float)(-(s_d[0] + s_d[1] + s_d[2] + s_d[3]) / (double)NTOT);
    }
}

extern "C" void kernel_launch(void* const* d_in, const int* in_sizes, int n_in,
                              void* d_out, int out_size, void* d_ws, size_t ws_size,
                              hipStream_t stream) {
    const float* input  = (const float*)d_in[0];  // [B,1,T,W,W] == flat [B,T,W,W]
    const float* target = (const float*)d_in[1];  // [B,T,W,W]
    float* out = (float*)d_out;

    int* arrive  = (int*)d_ws;                               // 256 ints
    int* done    = arrive + 256;                             // 1 int
    float4* blk  = (float4*)((char*)d_ws + 4096);            // 2048 float4
    double* bsum = (double*)((char*)d_ws + 4096 + NBLK * sizeof(float4));

    hipMemsetAsync(d_ws, 0, 4096, stream);   // zero counters (graph-capturable)
    floss_all<<<NBLK, 256, 0, stream>>>(input, target, arrive, done, blk, bsum, out);
}

// Round 5
// 300.695 us; speedup vs baseline: 1.7137x; 1.7137x over previous
//
#include <hip/hip_runtime.h>

// Problem constants (fixed by setup_inputs: B=16, T=16, W=256)
#define WDIM 256
#define FRAME (WDIM * WDIM)        // 65536 elems per frame
#define NFRAMES 256                // B*T
#define NTOT ((long long)NFRAMES * FRAME)  // 16777216
#define NBLK 2048                  // 8 sub-blocks per frame
#define SUBV4 2048                 // float4 per sub-block (32 KiB)

// ws layout:
//   [0,32768)       float4 blk[2048]  -- per-block stats (all rewritten by K1)
//   [32768,49152)   double bsum[2048] -- per-block partials (all rewritten by K2)
//   [49152,49156)   int done          -- completion ticket (memset 0 each call)

// K1: per-(frame,sub) stats. Each block reads 32 KiB of target into registers,
// computes block max AND tie stats (cnt, sum-row, sum-col) vs its OWN block
// max from the register copy. A block's stats are valid for the frame iff its
// bmax equals the frame max -- combined exactly in K2. No rescan, no atomics.
__global__ __launch_bounds__(256)
void floss_stats(const float* __restrict__ target, float4* __restrict__ blk) {
    const int bid = blockIdx.x;
    const int fid = bid >> 3, sub = bid & 7;
    const int tid = threadIdx.x;
    const int lane = tid & 63, wave = tid >> 6;

    const float4* __restrict__ t4 =
        (const float4*)(target + (size_t)fid * FRAME) + sub * SUBV4;

    // elem f = sub*8192 + k*1024 + tid*4 + j  ->  row = sub*32 + k*4 + (tid>>6),
    // col = (tid&63)*4 + j
    float4 tv[8];
    #pragma unroll
    for (int k = 0; k < 8; ++k) tv[k] = t4[k * 256 + tid];

    float lmax = -1.0f;
    #pragma unroll
    for (int k = 0; k < 8; ++k)
        lmax = fmaxf(lmax, fmaxf(fmaxf(tv[k].x, tv[k].y), fmaxf(tv[k].z, tv[k].w)));

    // block max: wave shfl reduce + tiny LDS combine
    float wm = lmax;
    #pragma unroll
    for (int off = 32; off > 0; off >>= 1) wm = fmaxf(wm, __shfl_down(wm, off));
    __shared__ float s_wm[4];
    __shared__ float s_st[4][3];
    if (lane == 0) s_wm[wave] = wm;
    __syncthreads();
    const float bmax = fmaxf(fmaxf(s_wm[0], s_wm[1]), fmaxf(s_wm[2], s_wm[3]));

    // tie stats vs block max, from registers (exact small-int float sums)
    float cnt = 0.0f, sr = 0.0f, sc = 0.0f;
    const float rowb = (float)(sub * 32 + (tid >> 6));
    const float colb = (float)((tid & 63) * 4);
    #pragma unroll
    for (int k = 0; k < 8; ++k) {
        const float row = rowb + (float)(4 * k);
        const float vv[4] = {tv[k].x, tv[k].y, tv[k].z, tv[k].w};
        #pragma unroll
        for (int j = 0; j < 4; ++j)
            if (vv[j] == bmax) { cnt += 1.0f; sr += row; sc += colb + (float)j; }
    }
    #pragma unroll
    for (int off = 32; off > 0; off >>= 1) {
        cnt += __shfl_down(cnt, off);
        sr  += __shfl_down(sr,  off);
        sc  += __shfl_down(sc,  off);
    }
    if (lane == 0) { s_st[wave][0] = cnt; s_st[wave][1] = sr; s_st[wave][2] = sc; }
    __syncthreads();
    if (tid == 0) {
        float c = 0.0f, r = 0.0f, cc = 0.0f;
        #pragma unroll
        for (int w = 0; w < 4; ++w) { c += s_st[w][0]; r += s_st[w][1]; cc += s_st[w][2]; }
        blk[bid] = make_float4(bmax, c, r, cc);
    }
}

// K2: weighted BCE + final reduce (last-block ticket folds the old K3).
// Combine the frame's 8 stat records (uniform scalar loads), then stream t+p
// once, double-buffered. High occupancy, no big LDS.
__global__ __launch_bounds__(256)
void floss_bce(const float* __restrict__ input, const float* __restrict__ target,
               const float4* __restrict__ blk, double* __restrict__ bsum,
               int* __restrict__ done, float* __restrict__ out) {
    const int bid = blockIdx.x;
    const int fid = bid >> 3, sub = bid & 7;
    const int tid = threadIdx.x;
    const int lane = tid & 63, wave = tid >> 6;

    const float4* __restrict__ t4 =
        (const float4*)(target + (size_t)fid * FRAME) + sub * SUBV4;
    const float4* __restrict__ p4 =
        (const float4*)(input + (size_t)fid * FRAME) + sub * SUBV4;

    // frame stats: max of 8 block maxes; sum stats of blocks matching it.
    // Exact float compares + exact small-int sums == round-2 values bitwise.
    float fm = -1.0f;
    float4 st[8];
    #pragma unroll
    for (int i = 0; i < 8; ++i) {
        st[i] = blk[(fid << 3) + i];            // uniform address -> s_load
        fm = fmaxf(fm, st[i].x);
    }
    float cnt = 0.0f, sr = 0.0f, sc = 0.0f;
    #pragma unroll
    for (int i = 0; i < 8; ++i)
        if (st[i].x == fm) { cnt += st[i].y; sr += st[i].z; sc += st[i].w; }
    const float rc = __builtin_amdgcn_rcpf(cnt);   // cnt: small exact int
    const float x = sr * rc;   // mean row
    const float y = sc * rc;   // mean col

    const float rowb = (float)(sub * 32 + (tid >> 6));
    float dc2[4];
    #pragma unroll
    for (int j = 0; j < 4; ++j) {
        const float d = (float)((tid & 63) * 4 + j) - y;
        dc2[j] = d * d;
    }

    // double-buffered stream of t+p (2 chunks in flight each)
    float4 tA = t4[tid],       pA = p4[tid];
    float4 tB = t4[256 + tid], pB = p4[256 + tid];

    float acc0 = 0.0f, acc1 = 0.0f;
    #pragma unroll
    for (int k = 0; k < 8; ++k) {
        const float4 tv = (k & 1) ? tB : tA;
        const float4 pv = (k & 1) ? pB : pA;
        if (k < 6) {
            if (k & 1) { tB = t4[(k + 2) * 256 + tid]; pB = p4[(k + 2) * 256 + tid]; }
            else       { tA = t4[(k + 2) * 256 + tid]; pA = p4[(k + 2) * 256 + tid]; }
        }
        const float dr = rowb + (float)(4 * k) - x;
        const float dr2 = dr * dr;
        const float tt[4] = {tv.x, tv.y, tv.z, tv.w};
        const float pp[4] = {pv.x, pv.y, pv.z, pv.w};
        #pragma unroll
        for (int j = 0; j < 4; ++j) {
            const float dist = __builtin_amdgcn_sqrtf(dr2 + dc2[j]);
            const float w = 256.0f * __builtin_amdgcn_rcpf(dist + 1.0f);
            const float p = pp[j];
            const float lp  = fmaxf(__logf(p), -100.0f);          // v_log_f32
            const float l1p = fmaxf(__logf(1.0f - p), -100.0f);   // exact 1-p for p>=0.5
            // t*lp + (1-t)*l1p == l1p + t*(lp - l1p)
            if (j & 1) acc1 += w * fmaf(tt[j], lp - l1p, l1p);
            else       acc0 += w * fmaf(tt[j], lp - l1p, l1p);
        }
    }

    float local = acc0 + acc1;
    #pragma unroll
    for (int off = 32; off > 0; off >>= 1) local += __shfl_down(local, off);
    __shared__ float s_acc[4];
    __shared__ int s_last;
    if (lane == 0) s_acc[wave] = local;
    __syncthreads();

    // publish partial; last-arriving block reduces all 2048 (no polling)
    if (tid == 0) {
        bsum[bid] = (double)(s_acc[0] + s_acc[1] + s_acc[2] + s_acc[3]);
        __threadfence();   // release: partial visible device-wide before ticket
        const int t = __hip_atomic_fetch_add(done, 1, __ATOMIC_ACQ_REL,
                                             __HIP_MEMORY_SCOPE_AGENT);
        s_last = (t == NBLK - 1) ? 1 : 0;
    }
    __syncthreads();
    if (s_last) {                       // exactly one block, block-uniform
        __threadfence();                // acquire: see all 2048 partials
        double v = 0.0;
        #pragma unroll
        for (int i = 0; i < 8; ++i) v += bsum[tid + 256 * i];
        #pragma unroll
        for (int off = 32; off > 0; off >>= 1) v += __shfl_down(v, off);
        __shared__ double sd[4];
        if (lane == 0) sd[wave] = v;
        __syncthreads();
        if (tid == 0)
            out[0] = (float)(-(sd[0] + sd[1] + sd[2] + sd[3]) / (double)NTOT);
    }
}

extern "C" void kernel_launch(void* const* d_in, const int* in_sizes, int n_in,
                              void* d_out, int out_size, void* d_ws, size_t ws_size,
                              hipStream_t stream) {
    const float* input  = (const float*)d_in[0];  // [B,1,T,W,W] == flat [B,T,W,W]
    const float* target = (const float*)d_in[1];  // [B,T,W,W]
    float* out = (float*)d_out;
    float4* blk  = (float4*)d_ws;                                   // 2048 float4
    double* bsum = (double*)((char*)d_ws + NBLK * sizeof(float4));  // 2048 doubles
    int* done    = (int*)((char*)d_ws + NBLK * (sizeof(float4) + sizeof(double)));

    hipMemsetAsync(done, 0, sizeof(int), stream);   // 4 B; graph-capturable
    floss_stats<<<NBLK, 256, 0, stream>>>(target, blk);
    floss_bce<<<NBLK, 256, 0, stream>>>(input, target, blk, bsum, done, out);
}

// Round 6
// 151.970 us; speedup vs baseline: 3.3908x; 1.9786x over previous
//
#include <hip/hip_runtime.h>

// Problem constants (fixed by setup_inputs: B=16, T=16, W=256)
#define WDIM 256
#define FRAME (WDIM * WDIM)        // 65536 elems per frame
#define NFRAMES 256                // B*T
#define NTOT ((long long)NFRAMES * FRAME)  // 16777216
#define NBLK 2048                  // 8 sub-blocks per frame
#define SUBV4 2048                 // float4 per sub-block (32 KiB)

// ws layout: float4 blk[2048] (32 KB) | double bsum[2048] (16 KB). 48 KB total,
// fully overwritten every call (no init kernel / memset needed).

// K1: per-(frame,sub) stats. Each block reads 32 KiB of target into registers
// (8 loads issued up front -> high MLP), computes block max AND tie stats
// (cnt, sum-row, sum-col) vs its OWN block max from the register copy. A
// block's stats are valid for the frame iff its bmax equals the frame max --
// combined exactly in K2. No rescan, no atomics.
__global__ __launch_bounds__(256)
void floss_stats(const float* __restrict__ target, float4* __restrict__ blk) {
    const int bid = blockIdx.x;
    const int fid = bid >> 3, sub = bid & 7;
    const int tid = threadIdx.x;
    const int lane = tid & 63, wave = tid >> 6;

    const float4* __restrict__ t4 =
        (const float4*)(target + (size_t)fid * FRAME) + sub * SUBV4;

    // elem f = sub*8192 + k*1024 + tid*4 + j  ->  row = sub*32 + k*4 + (tid>>6),
    // col = (tid&63)*4 + j
    float4 tv[8];
    #pragma unroll
    for (int k = 0; k < 8; ++k) tv[k] = t4[k * 256 + tid];

    float lmax = -1.0f;
    #pragma unroll
    for (int k = 0; k < 8; ++k)
        lmax = fmaxf(lmax, fmaxf(fmaxf(tv[k].x, tv[k].y), fmaxf(tv[k].z, tv[k].w)));

    // block max: wave shfl reduce + tiny LDS combine
    float wm = lmax;
    #pragma unroll
    for (int off = 32; off > 0; off >>= 1) wm = fmaxf(wm, __shfl_down(wm, off));
    __shared__ float s_wm[4];
    __shared__ float s_st[4][3];
    if (lane == 0) s_wm[wave] = wm;
    __syncthreads();
    const float bmax = fmaxf(fmaxf(s_wm[0], s_wm[1]), fmaxf(s_wm[2], s_wm[3]));

    // tie stats vs block max, from registers (exact small-int float sums)
    float cnt = 0.0f, sr = 0.0f, sc = 0.0f;
    const float rowb = (float)(sub * 32 + (tid >> 6));
    const float colb = (float)((tid & 63) * 4);
    #pragma unroll
    for (int k = 0; k < 8; ++k) {
        const float row = rowb + (float)(4 * k);
        const float vv[4] = {tv[k].x, tv[k].y, tv[k].z, tv[k].w};
        #pragma unroll
        for (int j = 0; j < 4; ++j)
            if (vv[j] == bmax) { cnt += 1.0f; sr += row; sc += colb + (float)j; }
    }
    #pragma unroll
    for (int off = 32; off > 0; off >>= 1) {
        cnt += __shfl_down(cnt, off);
        sr  += __shfl_down(sr,  off);
        sc  += __shfl_down(sc,  off);
    }
    if (lane == 0) { s_st[wave][0] = cnt; s_st[wave][1] = sr; s_st[wave][2] = sc; }
    __syncthreads();
    if (tid == 0) {
        float c = 0.0f, r = 0.0f, cc = 0.0f;
        #pragma unroll
        for (int w = 0; w < 4; ++w) { c += s_st[w][0]; r += s_st[w][1]; cc += s_st[w][2]; }
        blk[bid] = make_float4(bmax, c, r, cc);
    }
}

// K2: weighted BCE. ALL 16 chunk loads (8 target + 8 input) are issued up
// front into static-indexed register arrays (K1's proven high-MLP pattern,
// ~16 KB in flight per wave); the frame-stats combine runs while they fly.
// Then pure compute. No atomics, no big LDS.
__global__ __launch_bounds__(256)
void floss_bce(const float* __restrict__ input, const float* __restrict__ target,
               const float4* __restrict__ blk, double* __restrict__ bsum) {
    const int bid = blockIdx.x;
    const int fid = bid >> 3, sub = bid & 7;
    const int tid = threadIdx.x;
    const int lane = tid & 63, wave = tid >> 6;

    const float4* __restrict__ t4 =
        (const float4*)(target + (size_t)fid * FRAME) + sub * SUBV4;
    const float4* __restrict__ p4 =
        (const float4*)(input + (size_t)fid * FRAME) + sub * SUBV4;

    // issue the full 32 KiB stream first: 16 independent dwordx4 loads
    float4 tv[8], pv[8];
    #pragma unroll
    for (int k = 0; k < 8; ++k) tv[k] = t4[k * 256 + tid];
    #pragma unroll
    for (int k = 0; k < 8; ++k) pv[k] = p4[k * 256 + tid];

    // frame stats: max of 8 block maxes; sum stats of blocks matching it.
    // Uniform addresses -> s_load; computes while vector loads are in flight.
    // Exact float compares + exact small-int sums == round-2 values bitwise.
    float fm = -1.0f;
    float4 st[8];
    #pragma unroll
    for (int i = 0; i < 8; ++i) {
        st[i] = blk[(fid << 3) + i];
        fm = fmaxf(fm, st[i].x);
    }
    float cnt = 0.0f, sr = 0.0f, sc = 0.0f;
    #pragma unroll
    for (int i = 0; i < 8; ++i)
        if (st[i].x == fm) { cnt += st[i].y; sr += st[i].z; sc += st[i].w; }
    const float rc = __builtin_amdgcn_rcpf(cnt);   // cnt: small exact int
    const float x = sr * rc;   // mean row
    const float y = sc * rc;   // mean col

    const float rowb = (float)(sub * 32 + (tid >> 6));
    float dc2[4];
    #pragma unroll
    for (int j = 0; j < 4; ++j) {
        const float d = (float)((tid & 63) * 4 + j) - y;
        dc2[j] = d * d;
    }

    float acc0 = 0.0f, acc1 = 0.0f;
    #pragma unroll
    for (int k = 0; k < 8; ++k) {
        const float dr = rowb + (float)(4 * k) - x;
        const float dr2 = dr * dr;
        const float tt[4] = {tv[k].x, tv[k].y, tv[k].z, tv[k].w};
        const float pp[4] = {pv[k].x, pv[k].y, pv[k].z, pv[k].w};
        #pragma unroll
        for (int j = 0; j < 4; ++j) {
            const float dist = __builtin_amdgcn_sqrtf(dr2 + dc2[j]);
            const float w = 256.0f * __builtin_amdgcn_rcpf(dist + 1.0f);
            const float p = pp[j];
            const float lp  = fmaxf(__logf(p), -100.0f);          // v_log_f32
            const float l1p = fmaxf(__logf(1.0f - p), -100.0f);   // exact 1-p for p>=0.5
            // t*lp + (1-t)*l1p == l1p + t*(lp - l1p)
            if (j & 1) acc1 += w * fmaf(tt[j], lp - l1p, l1p);
            else       acc0 += w * fmaf(tt[j], lp - l1p, l1p);
        }
    }

    float local = acc0 + acc1;
    #pragma unroll
    for (int off = 32; off > 0; off >>= 1) local += __shfl_down(local, off);
    __shared__ float s_acc[4];
    if (lane == 0) s_acc[wave] = local;
    __syncthreads();
    if (tid == 0)
        bsum[bid] = (double)(s_acc[0] + s_acc[1] + s_acc[2] + s_acc[3]);
}

// K3: reduce 2048 per-block doubles, write final loss. (~4 us; 25x cheaper
// than any single-line device-wide ticket -- see round-5 post-mortem.)
__global__ __launch_bounds__(1024)
void floss_final(const double* __restrict__ bsum, float* __restrict__ out) {
    const int tid = threadIdx.x;
    const int lane = tid & 63, wave = tid >> 6;
    double v = bsum[tid] + bsum[tid + 1024];
    #pragma unroll
    for (int off = 32; off > 0; off >>= 1) v += __shfl_down(v, off);
    __shared__ double sd[16];
    if (lane == 0) sd[wave] = v;
    __syncthreads();
    if (tid == 0) {
        double s = 0.0;
        #pragma unroll
        for (int w = 0; w < 16; ++w) s += sd[w];
        out[0] = (float)(-s / (double)NTOT);
    }
}

extern "C" void kernel_launch(void* const* d_in, const int* in_sizes, int n_in,
                              void* d_out, int out_size, void* d_ws, size_t ws_size,
                              hipStream_t stream) {
    const float* input  = (const float*)d_in[0];  // [B,1,T,W,W] == flat [B,T,W,W]
    const float* target = (const float*)d_in[1];  // [B,T,W,W]
    float* out = (float*)d_out;
    float4* blk  = (float4*)d_ws;                          // 2048 float4 (32 KB)
    double* bsum = (double*)((char*)d_ws + NBLK * sizeof(float4)); // 2048 doubles

    floss_stats<<<NBLK, 256, 0, stream>>>(target, blk);
    floss_bce<<<NBLK, 256, 0, stream>>>(input, target, blk, bsum);
    floss_final<<<1, 1024, 0, stream>>>(bsum, out);
}